// Round 11
// baseline (333.868 us; speedup 1.0000x reference)
//
#include <hip/hip_runtime.h>
#include <cstdint>
#include <cstddef>

#define N_NODES 50000
#define N_EDGES 800000
#define N_ETOT  850000   // E + N self-loops
#define DIM     128
#define NHEAD   8
#define NGRAPH  100
#define NLAT    64
#define NEG_SLOPE 0.2f
#define BN_EPS  1e-5f

#define NBUCKET 196      // ceil(50000/256): bucket = dst>>8
#define CAP     5120     // slots per bucket (mean 4352)
#define EPB     4096     // edges per k_bin block
#define POOL_CHUNK 50

#define XSTR 136         // padded LDS row stride in bf16 elems (272B, 16B-mult, 2-way banks)

typedef unsigned int   u32;
typedef unsigned short u16;
typedef short  bf16x8 __attribute__((ext_vector_type(8)));
typedef float  f32x4  __attribute__((ext_vector_type(4)));

__device__ __forceinline__ float b2f(u16 u){
    union { u32 i; float f; } v; v.i = ((u32)u) << 16; return v.f;
}
__device__ __forceinline__ u16 f2b(float f){
    union { float f; u32 i; } v; v.f = f;
    u32 u = v.i;
    u32 r = (u + 0x7fffu + ((u >> 16) & 1u)) >> 16;
    return (u16)r;
}

// ---------------- prelude: W transpose + workspace zeroing (folds 2 memsets) --

__launch_bounds__(256)
__global__ void k_pre(const float* __restrict__ Wp, u16* __restrict__ wt_g,
                      int* __restrict__ bucket_cur, float* __restrict__ pooled){
    int gtid = blockIdx.x * 256 + threadIdx.x;      // 24*256 = 6144 threads
    // zero bucket_cur (196 ints)
    if (gtid < NBUCKET) bucket_cur[gtid] = 0;
    // zero pooled (12800 floats)
    for (int i = gtid; i < NGRAPH * 128; i += 6144) pooled[i] = 0.f;
    // transpose Wp[l][k][n] fp32 -> wt_g[l][n][k] bf16 (3*128*16 = 6144 tasks)
    int layer = gtid >> 11;
    int rem   = gtid & 2047;
    int n  = rem >> 4;
    int kc = rem & 15;
    const float* src = Wp + layer * 16384;
    u16 tmp[8];
    #pragma unroll
    for (int j = 0; j < 8; j++)
        tmp[j] = f2b(src[(kc * 8 + j) * 128 + n]);
    *(uint4*)(wt_g + (size_t)layer * 16384 + n * 128 + kc * 8) = *(uint4*)tmp;
}

// ---------------- binned CSR build ----------------

__launch_bounds__(256)
__global__ void k_bin(const int* __restrict__ ei, int* __restrict__ bucket_cur,
                      u32* __restrict__ binned){
    __shared__ u32 stage[EPB];          // 16 KB
    __shared__ int hist[256], scanb[256], curb[256], gbase[256];
    const int tid = threadIdx.x;
    const int e0  = blockIdx.x * EPB;

    hist[tid] = 0;
    __syncthreads();

    #pragma unroll
    for (int j = 0; j < EPB / 256; j++) {
        int e = e0 + j * 256 + tid;
        if (e < N_ETOT) {
            int d = (e < N_EDGES) ? ei[N_EDGES + e] : (e - N_EDGES);
            atomicAdd(&hist[d >> 8], 1);
        }
    }
    __syncthreads();

    __shared__ int s[256];
    s[tid] = hist[tid];
    __syncthreads();
    for (int o = 1; o < 256; o <<= 1) {
        int t = (tid >= o) ? s[tid - o] : 0;
        __syncthreads();
        s[tid] += t;
        __syncthreads();
    }
    scanb[tid] = s[tid] - hist[tid];
    curb[tid]  = 0;
    __syncthreads();

    #pragma unroll
    for (int j = 0; j < EPB / 256; j++) {
        int e = e0 + j * 256 + tid;
        if (e < N_ETOT) {
            int src, d;
            if (e < N_EDGES) { src = ei[e]; d = ei[N_EDGES + e]; }
            else             { src = e - N_EDGES; d = src; }
            int b = d >> 8;
            int r = atomicAdd(&curb[b], 1);
            stage[scanb[b] + r] = (u32)src | ((u32)(d & 255) << 16) | ((u32)b << 24);
        }
    }
    __syncthreads();

    if (tid < NBUCKET && hist[tid] > 0)
        gbase[tid] = atomicAdd(&bucket_cur[tid], hist[tid]);
    __syncthreads();

    int nvalid = min(EPB, N_ETOT - e0);
    for (int i = tid; i < nvalid; i += 256) {
        u32 rec = stage[i];
        int b = rec >> 24;
        int pos = gbase[b] + (i - scanb[b]);
        if (pos < CAP) binned[(size_t)b * CAP + pos] = rec;
    }
}

__launch_bounds__(256)
__global__ void k_bucket(const int* __restrict__ bucket_cur, const u32* __restrict__ binned,
                         int* __restrict__ rowbeg, int* __restrict__ rowend,
                         int* __restrict__ csr){
    __shared__ int deg[256], off[256], cur[256], s[256];
    const int tid = threadIdx.x;
    const int b   = blockIdx.x;
    const int cnt = min(bucket_cur[b], CAP);
    const int base = b * CAP;

    deg[tid] = 0;
    __syncthreads();
    for (int i = tid; i < cnt; i += 256)
        atomicAdd(&deg[(binned[base + i] >> 16) & 255], 1);
    __syncthreads();

    s[tid] = deg[tid];
    __syncthreads();
    for (int o = 1; o < 256; o <<= 1) {
        int t = (tid >= o) ? s[tid - o] : 0;
        __syncthreads();
        s[tid] += t;
        __syncthreads();
    }
    off[tid] = s[tid] - deg[tid];
    cur[tid] = s[tid] - deg[tid];
    __syncthreads();

    int node = b * 256 + tid;
    if (node < N_NODES) {
        rowbeg[node] = base + off[tid];
        rowend[node] = base + off[tid] + deg[tid];
    }

    for (int i = tid; i < cnt; i += 256) {
        u32 rec = binned[base + i];
        int l = (rec >> 16) & 255;
        int p = atomicAdd(&cur[l], 1);
        csr[base + p] = (int)(rec & 0xffffu);
    }
}

// ---------------- MFMA GEMM: x @ W -> hp (bf16) + fused alpha logits ----------
// 64 rows/block, 4 waves, 8 head-tiles each, K=128 in 4 mfma steps.
// A from LDS (xs); B frags straight from global wt_g (32 KB, L2-hot across
// all 782 blocks — skipping the LDS stage drops LDS 51->17 KB, ~3x blocks/CU).

template<bool BF16IN>
__launch_bounds__(256)
__global__ void k_gemm(const void* __restrict__ xin, const u16* __restrict__ wt_g,
                       const float* __restrict__ asrc, const float* __restrict__ adst,
                       u16* __restrict__ hp,
                       float* __restrict__ as_, float* __restrict__ ad_){
    __shared__ u16 xs[64 * XSTR];    // 17.0 KB (input tile, then output tile)
    const int tid = threadIdx.x;
    const int r0  = blockIdx.x * 64;

    if (BF16IN) {
        const u16* x = (const u16*)xin;
        for (int c = tid; c < 64 * 16; c += 256) {
            int row = r0 + (c >> 4);
            uint4 v = make_uint4(0, 0, 0, 0);
            if (row < N_NODES) v = *(const uint4*)(x + (size_t)row * 128 + (c & 15) * 8);
            *(uint4*)(xs + (c >> 4) * XSTR + (c & 15) * 8) = v;
        }
    } else {
        const float* x = (const float*)xin;
        for (int c = tid; c < 64 * 16; c += 256) {
            int row = r0 + (c >> 4);
            u16 t[8] = {0,0,0,0,0,0,0,0};
            if (row < N_NODES) {
                const float* p = x + (size_t)row * 128 + (c & 15) * 8;
                #pragma unroll
                for (int j = 0; j < 8; j++) t[j] = f2b(p[j]);
            }
            *(uint4*)(xs + (c >> 4) * XSTR + (c & 15) * 8) = *(uint4*)t;
        }
    }
    __syncthreads();

    const int lane = tid & 63;
    const int wv   = tid >> 6;
    const int m    = lane & 15;
    const int quad = lane >> 4;

    const u16* arow = xs + (16 * wv + m) * XSTR + quad * 8;
    bf16x8 a0 = *(const bf16x8*)(arow);
    bf16x8 a1 = *(const bf16x8*)(arow + 32);
    bf16x8 a2 = *(const bf16x8*)(arow + 64);
    bf16x8 a3 = *(const bf16x8*)(arow + 96);
    __syncthreads();    // xs reused for C below; A frags already in regs

    #pragma unroll
    for (int c = 0; c < 8; c++) {
        const u16* brow = wt_g + (16 * c + m) * 128 + quad * 8;
        f32x4 acc = {0.f, 0.f, 0.f, 0.f};
        acc = __builtin_amdgcn_mfma_f32_16x16x32_bf16(a0, *(const bf16x8*)(brow),      acc, 0, 0, 0);
        acc = __builtin_amdgcn_mfma_f32_16x16x32_bf16(a1, *(const bf16x8*)(brow + 32), acc, 0, 0, 0);
        acc = __builtin_amdgcn_mfma_f32_16x16x32_bf16(a2, *(const bf16x8*)(brow + 64), acc, 0, 0, 0);
        acc = __builtin_amdgcn_mfma_f32_16x16x32_bf16(a3, *(const bf16x8*)(brow + 96), acc, 0, 0, 0);
        u16* orow = xs + (16 * wv + quad * 4) * XSTR + 16 * c + m;
        orow[0]        = f2b(acc[0]);
        orow[XSTR]     = f2b(acc[1]);
        orow[2 * XSTR] = f2b(acc[2]);
        orow[3 * XSTR] = f2b(acc[3]);
    }
    __syncthreads();

    for (int t = tid; t < 512; t += 256) {
        int row = t >> 3, h = t & 7;
        int gr = r0 + row;
        if (gr >= N_NODES) continue;
        const u16* hr = xs + row * XSTR + h * 16;
        const float* av = asrc + h * 16;
        const float* bv = adst + h * 16;
        float s0 = 0.f, s1 = 0.f;
        #pragma unroll
        for (int j = 0; j < 16; j++) {
            float v = b2f(hr[j]);
            s0 = fmaf(v, av[j], s0);
            s1 = fmaf(v, bv[j], s1);
        }
        as_[(size_t)gr * 8 + h] = s0;
        ad_[(size_t)gr * 8 + h] = s1;
    }

    for (int t = tid; t < 1024; t += 256) {
        int row = t >> 4, ch = t & 15;
        int gr = r0 + row;
        if (gr >= N_NODES) continue;
        *(uint4*)(hp + (size_t)gr * 128 + ch * 8) = *(const uint4*)(xs + row * XSTR + ch * 8);
    }
}

// ---------------- per-layer: single-pass segment softmax + aggregate ----------
// One wave/node; 16 edges in flight per iteration (4 independent gather chains).

__launch_bounds__(256)
__global__ void k_agg(const int* __restrict__ rowbeg, const int* __restrict__ rowend,
                      const int* __restrict__ csr,
                      const float* __restrict__ as_, const float* __restrict__ ad_,
                      const uint4* __restrict__ hp4, const float* __restrict__ bias,
                      u16* __restrict__ xout){
    const int lane = threadIdx.x & 63;
    const int wid  = threadIdx.x >> 6;
    const int n    = blockIdx.x * 4 + wid;
    if (n >= N_NODES) return;
    const int beg = rowbeg[n], end = rowend[n];

    const int q  = lane >> 4;       // edge slot 0..3
    const int li = lane & 15;       // cols 8*li .. 8*li+7
    const int h  = li >> 1;         // head
    const float adn = ad_[(size_t)n * 8 + h];

    float acc[8];
    #pragma unroll
    for (int j = 0; j < 8; j++) acc[j] = 0.f;
    float den = 0.f;

    for (int e0 = beg; e0 < end; e0 += 16) {
        int eA = e0 + q, eB = eA + 4, eC = eA + 8, eD = eA + 12;
        int sA = csr[min(eA, end - 1)];
        int sB = csr[min(eB, end - 1)];
        int sC = csr[min(eC, end - 1)];
        int sD = csr[min(eD, end - 1)];
        float vA = as_[(size_t)sA * 8 + h] + adn;
        float vB = as_[(size_t)sB * 8 + h] + adn;
        float vC = as_[(size_t)sC * 8 + h] + adn;
        float vD = as_[(size_t)sD * 8 + h] + adn;
        uint4 pA = hp4[(size_t)sA * 16 + li];
        uint4 pB = hp4[(size_t)sB * 16 + li];
        uint4 pC = hp4[(size_t)sC * 16 + li];
        uint4 pD = hp4[(size_t)sD * 16 + li];
        vA = vA > 0.f ? vA : NEG_SLOPE * vA;
        vB = vB > 0.f ? vB : NEG_SLOPE * vB;
        vC = vC > 0.f ? vC : NEG_SLOPE * vC;
        vD = vD > 0.f ? vD : NEG_SLOPE * vD;
        float wA = (eA < end) ? __expf(vA) : 0.f;
        float wB = (eB < end) ? __expf(vB) : 0.f;
        float wC = (eC < end) ? __expf(vC) : 0.f;
        float wD = (eD < end) ? __expf(vD) : 0.f;
        den += (wA + wB) + (wC + wD);
        acc[0] = fmaf(wA, b2f((u16)(pA.x & 0xffff)), acc[0]);
        acc[1] = fmaf(wA, b2f((u16)(pA.x >> 16)),    acc[1]);
        acc[2] = fmaf(wA, b2f((u16)(pA.y & 0xffff)), acc[2]);
        acc[3] = fmaf(wA, b2f((u16)(pA.y >> 16)),    acc[3]);
        acc[4] = fmaf(wA, b2f((u16)(pA.z & 0xffff)), acc[4]);
        acc[5] = fmaf(wA, b2f((u16)(pA.z >> 16)),    acc[5]);
        acc[6] = fmaf(wA, b2f((u16)(pA.w & 0xffff)), acc[6]);
        acc[7] = fmaf(wA, b2f((u16)(pA.w >> 16)),    acc[7]);
        acc[0] = fmaf(wB, b2f((u16)(pB.x & 0xffff)), acc[0]);
        acc[1] = fmaf(wB, b2f((u16)(pB.x >> 16)),    acc[1]);
        acc[2] = fmaf(wB, b2f((u16)(pB.y & 0xffff)), acc[2]);
        acc[3] = fmaf(wB, b2f((u16)(pB.y >> 16)),    acc[3]);
        acc[4] = fmaf(wB, b2f((u16)(pB.z & 0xffff)), acc[4]);
        acc[5] = fmaf(wB, b2f((u16)(pB.z >> 16)),    acc[5]);
        acc[6] = fmaf(wB, b2f((u16)(pB.w & 0xffff)), acc[6]);
        acc[7] = fmaf(wB, b2f((u16)(pB.w >> 16)),    acc[7]);
        acc[0] = fmaf(wC, b2f((u16)(pC.x & 0xffff)), acc[0]);
        acc[1] = fmaf(wC, b2f((u16)(pC.x >> 16)),    acc[1]);
        acc[2] = fmaf(wC, b2f((u16)(pC.y & 0xffff)), acc[2]);
        acc[3] = fmaf(wC, b2f((u16)(pC.y >> 16)),    acc[3]);
        acc[4] = fmaf(wC, b2f((u16)(pC.z & 0xffff)), acc[4]);
        acc[5] = fmaf(wC, b2f((u16)(pC.z >> 16)),    acc[5]);
        acc[6] = fmaf(wC, b2f((u16)(pC.w & 0xffff)), acc[6]);
        acc[7] = fmaf(wC, b2f((u16)(pC.w >> 16)),    acc[7]);
        acc[0] = fmaf(wD, b2f((u16)(pD.x & 0xffff)), acc[0]);
        acc[1] = fmaf(wD, b2f((u16)(pD.x >> 16)),    acc[1]);
        acc[2] = fmaf(wD, b2f((u16)(pD.y & 0xffff)), acc[2]);
        acc[3] = fmaf(wD, b2f((u16)(pD.y >> 16)),    acc[3]);
        acc[4] = fmaf(wD, b2f((u16)(pD.z & 0xffff)), acc[4]);
        acc[5] = fmaf(wD, b2f((u16)(pD.z >> 16)),    acc[5]);
        acc[6] = fmaf(wD, b2f((u16)(pD.w & 0xffff)), acc[6]);
        acc[7] = fmaf(wD, b2f((u16)(pD.w >> 16)),    acc[7]);
    }

    #pragma unroll
    for (int j = 0; j < 8; j++) {
        acc[j] += __shfl_xor(acc[j], 16);
        acc[j] += __shfl_xor(acc[j], 32);
    }
    den += __shfl_xor(den, 16);
    den += __shfl_xor(den, 32);

    if (q == 0) {
        const float inv = 1.f / (den + 1e-16f);
        const float4 b0 = *(const float4*)(bias + 8 * li);
        const float4 b1 = *(const float4*)(bias + 8 * li + 4);
        float o[8];
        o[0] = acc[0] * inv + b0.x; o[1] = acc[1] * inv + b0.y;
        o[2] = acc[2] * inv + b0.z; o[3] = acc[3] * inv + b0.w;
        o[4] = acc[4] * inv + b1.x; o[5] = acc[5] * inv + b1.y;
        o[6] = acc[6] * inv + b1.z; o[7] = acc[7] * inv + b1.w;
        #pragma unroll
        for (int j = 0; j < 8; j++)
            o[j] = o[j] > 0.f ? o[j] : (__expf(o[j]) - 1.f);   // ELU
        uint4 p;
        p.x = (u32)f2b(o[0]) | ((u32)f2b(o[1]) << 16);
        p.y = (u32)f2b(o[2]) | ((u32)f2b(o[3]) << 16);
        p.z = (u32)f2b(o[4]) | ((u32)f2b(o[5]) << 16);
        p.w = (u32)f2b(o[6]) | ((u32)f2b(o[7]) << 16);
        *(uint4*)(xout + (size_t)n * 128 + 8 * li) = p;
    }
}

// ---------------- pooling (bf16 input, sorted batch) / fused BN+FC ----------

__global__ void k_pool(const u16* __restrict__ x, const int* __restrict__ batch,
                       float* __restrict__ pooled){
    int tid = threadIdx.x;             // 128 = feature
    int n0 = blockIdx.x * POOL_CHUNK;
    int nend = min(n0 + POOL_CHUNK, N_NODES);
    float acc = 0.f;
    int cur = batch[n0];
    for (int n = n0; n < nend; n++) {
        int g = batch[n];
        if (g != cur) {
            atomicAdd(&pooled[cur * 128 + tid], acc);
            acc = 0.f; cur = g;
        }
        acc += b2f(x[(size_t)n * 128 + tid]);
    }
    atomicAdd(&pooled[cur * 128 + tid], acc);
}

// one block per graph; per-block redundant BN stats (pooled is 51KB, L2-hot)
__launch_bounds__(128)
__global__ void k_bnfc(const float* __restrict__ pooled, const float* __restrict__ gamma,
                       const float* __restrict__ beta, const float* __restrict__ fw,
                       const float* __restrict__ fb, float* __restrict__ out){
    __shared__ float sn[128];
    const int g = blockIdx.x, f = threadIdx.x;
    float mu = 0.f;
    for (int i = 0; i < NGRAPH; i++) mu += pooled[i * 128 + f];
    mu *= (1.f / NGRAPH);
    float var = 0.f;
    for (int i = 0; i < NGRAPH; i++) { float d = pooled[i * 128 + f] - mu; var += d * d; }
    var *= (1.f / NGRAPH);
    const float rs = rsqrtf(var + BN_EPS);
    sn[f] = (pooled[g * 128 + f] - mu) * rs * gamma[f] + beta[f];
    __syncthreads();
    if (f < NLAT) {
        float acc = fb[f];
        const float4* wr = (const float4*)(fw + f * 128);
        #pragma unroll
        for (int k = 0; k < 32; k++) {
            float4 w = wr[k];
            const float* nv = sn + 4 * k;
            acc = fmaf(nv[0], w.x, acc);
            acc = fmaf(nv[1], w.y, acc);
            acc = fmaf(nv[2], w.z, acc);
            acc = fmaf(nv[3], w.w, acc);
        }
        out[g * 64 + f] = acc;
    }
}

// ---------------- launch ----------------

extern "C" void kernel_launch(void* const* d_in, const int* in_sizes, int n_in,
                              void* d_out, int out_size, void* d_ws, size_t ws_size,
                              hipStream_t stream) {
    const float* x0    = (const float*)d_in[0];
    const int*   ei    = (const int*)d_in[1];
    const int*   batch = (const int*)d_in[2];
    const float* Wp    = (const float*)d_in[3];
    const float* asrc  = (const float*)d_in[4];
    const float* adst  = (const float*)d_in[5];
    const float* bias  = (const float*)d_in[6];
    const float* gamma = (const float*)d_in[7];
    const float* beta  = (const float*)d_in[8];
    const float* fw    = (const float*)d_in[9];
    const float* fb    = (const float*)d_in[10];
    float* out = (float*)d_out;

    char* w = (char*)d_ws;
    size_t off = 0;
    auto take = [&](size_t bytes) -> char* {
        char* p = w + off;
        off += (bytes + 255) & ~(size_t)255;
        return p;
    };
    int*   rowbeg  = (int*)take((size_t)N_NODES * 4);
    int*   rowend  = (int*)take((size_t)N_NODES * 4);
    int*   bucket_cur = (int*)take(NBUCKET * 4);
    u32*   binned  = (u32*)take((size_t)NBUCKET * CAP * 4);
    int*   csr     = (int*)take((size_t)NBUCKET * CAP * 4);
    u16*   wt_g    = (u16*)take((size_t)3 * 128 * 128 * 2);
    u16*   hp      = (u16*)take((size_t)N_NODES * 128 * 2);
    float* as_     = (float*)take((size_t)N_NODES * 8 * 4);
    float* ad_     = (float*)take((size_t)N_NODES * 8 * 4);
    u16*   xb1     = (u16*)take((size_t)N_NODES * 128 * 2);
    u16*   xb2     = (u16*)take((size_t)N_NODES * 128 * 2);
    float* pooled  = (float*)take((size_t)NGRAPH * 128 * 4);

    // prelude (W transpose + zero bucket_cur/pooled), then binned CSR build
    k_pre   <<<24, 256, 0, stream>>>(Wp, wt_g, bucket_cur, pooled);
    k_bin   <<<(N_ETOT + EPB - 1) / EPB, 256, 0, stream>>>(ei, bucket_cur, binned);
    k_bucket<<<NBUCKET, 256, 0, stream>>>(bucket_cur, binned, rowbeg, rowend, csr);

    const int gblk = (N_NODES + 63) / 64;
    const int ablk = (N_NODES + 3) / 4;

    // layer 0 (fp32 input)
    k_gemm<false><<<gblk, 256, 0, stream>>>(x0, wt_g, asrc, adst, hp, as_, ad_);
    k_agg<<<ablk, 256, 0, stream>>>(rowbeg, rowend, csr, as_, ad_,
                                    (const uint4*)hp, bias, xb1);
    // layer 1 (bf16 input)
    k_gemm<true><<<gblk, 256, 0, stream>>>(xb1, wt_g + 16384, asrc + 128, adst + 128,
                                           hp, as_, ad_);
    k_agg<<<ablk, 256, 0, stream>>>(rowbeg, rowend, csr, as_, ad_,
                                    (const uint4*)hp, bias + 128, xb2);
    // layer 2 (bf16 input)
    k_gemm<true><<<gblk, 256, 0, stream>>>(xb2, wt_g + 32768, asrc + 256, adst + 256,
                                           hp, as_, ad_);
    k_agg<<<ablk, 256, 0, stream>>>(rowbeg, rowend, csr, as_, ad_,
                                    (const uint4*)hp, bias + 256, xb1);

    // pool -> fused BN+FC
    k_pool<<<(N_NODES + POOL_CHUNK - 1) / POOL_CHUNK, 128, 0, stream>>>(xb1, batch, pooled);
    k_bnfc<<<NGRAPH, 128, 0, stream>>>(pooled, gamma, beta, fw, fb, out);
}

// Round 12
// 309.138 us; speedup vs baseline: 1.0800x; 1.0800x over previous
//
#include <hip/hip_runtime.h>
#include <cstdint>
#include <cstddef>

#define N_NODES 50000
#define N_EDGES 800000
#define N_ETOT  850000   // E + N self-loops
#define DIM     128
#define NHEAD   8
#define NGRAPH  100
#define NLAT    64
#define NEG_SLOPE 0.2f
#define BN_EPS  1e-5f

#define NBUCKET 196      // ceil(50000/256): bucket = dst>>8
#define CAP     5120     // slots per bucket (mean 4352)
#define EPB     4096     // edges per k_bin block
#define POOL_CHUNK 50

#define XSTR 136         // padded LDS row stride in bf16 elems (272B, 16B-mult, 2-way banks)

typedef unsigned int   u32;
typedef unsigned short u16;
typedef short  bf16x8 __attribute__((ext_vector_type(8)));
typedef float  f32x4  __attribute__((ext_vector_type(4)));

__device__ __forceinline__ float b2f(u16 u){
    union { u32 i; float f; } v; v.i = ((u32)u) << 16; return v.f;
}
__device__ __forceinline__ u16 f2b(float f){
    union { float f; u32 i; } v; v.f = f;
    u32 u = v.i;
    u32 r = (u + 0x7fffu + ((u >> 16) & 1u)) >> 16;
    return (u16)r;
}

// ---------------- prelude: W transpose + workspace zeroing (folds 2 memsets) --

__launch_bounds__(256)
__global__ void k_pre(const float* __restrict__ Wp, u16* __restrict__ wt_g,
                      int* __restrict__ bucket_cur, float* __restrict__ pooled){
    int gtid = blockIdx.x * 256 + threadIdx.x;      // 24*256 = 6144 threads
    if (gtid < NBUCKET) bucket_cur[gtid] = 0;
    for (int i = gtid; i < NGRAPH * 128; i += 6144) pooled[i] = 0.f;
    int layer = gtid >> 11;
    int rem   = gtid & 2047;
    int n  = rem >> 4;
    int kc = rem & 15;
    const float* src = Wp + layer * 16384;
    u16 tmp[8];
    #pragma unroll
    for (int j = 0; j < 8; j++)
        tmp[j] = f2b(src[(kc * 8 + j) * 128 + n]);
    *(uint4*)(wt_g + (size_t)layer * 16384 + n * 128 + kc * 8) = *(uint4*)tmp;
}

// ---------------- binned CSR build ----------------

__launch_bounds__(256)
__global__ void k_bin(const int* __restrict__ ei, int* __restrict__ bucket_cur,
                      u32* __restrict__ binned){
    __shared__ u32 stage[EPB];          // 16 KB
    __shared__ int hist[256], scanb[256], curb[256], gbase[256];
    const int tid = threadIdx.x;
    const int e0  = blockIdx.x * EPB;

    hist[tid] = 0;
    __syncthreads();

    #pragma unroll
    for (int j = 0; j < EPB / 256; j++) {
        int e = e0 + j * 256 + tid;
        if (e < N_ETOT) {
            int d = (e < N_EDGES) ? ei[N_EDGES + e] : (e - N_EDGES);
            atomicAdd(&hist[d >> 8], 1);
        }
    }
    __syncthreads();

    __shared__ int s[256];
    s[tid] = hist[tid];
    __syncthreads();
    for (int o = 1; o < 256; o <<= 1) {
        int t = (tid >= o) ? s[tid - o] : 0;
        __syncthreads();
        s[tid] += t;
        __syncthreads();
    }
    scanb[tid] = s[tid] - hist[tid];
    curb[tid]  = 0;
    __syncthreads();

    #pragma unroll
    for (int j = 0; j < EPB / 256; j++) {
        int e = e0 + j * 256 + tid;
        if (e < N_ETOT) {
            int src, d;
            if (e < N_EDGES) { src = ei[e]; d = ei[N_EDGES + e]; }
            else             { src = e - N_EDGES; d = src; }
            int b = d >> 8;
            int r = atomicAdd(&curb[b], 1);
            stage[scanb[b] + r] = (u32)src | ((u32)(d & 255) << 16) | ((u32)b << 24);
        }
    }
    __syncthreads();

    if (tid < NBUCKET && hist[tid] > 0)
        gbase[tid] = atomicAdd(&bucket_cur[tid], hist[tid]);
    __syncthreads();

    int nvalid = min(EPB, N_ETOT - e0);
    for (int i = tid; i < nvalid; i += 256) {
        u32 rec = stage[i];
        int b = rec >> 24;
        int pos = gbase[b] + (i - scanb[b]);
        if (pos < CAP) binned[(size_t)b * CAP + pos] = rec;
    }
}

__launch_bounds__(256)
__global__ void k_bucket(const int* __restrict__ bucket_cur, const u32* __restrict__ binned,
                         int* __restrict__ rowbeg, int* __restrict__ rowend,
                         int* __restrict__ csr){
    __shared__ int deg[256], off[256], cur[256], s[256];
    const int tid = threadIdx.x;
    const int b   = blockIdx.x;
    const int cnt = min(bucket_cur[b], CAP);
    const int base = b * CAP;

    deg[tid] = 0;
    __syncthreads();
    for (int i = tid; i < cnt; i += 256)
        atomicAdd(&deg[(binned[base + i] >> 16) & 255], 1);
    __syncthreads();

    s[tid] = deg[tid];
    __syncthreads();
    for (int o = 1; o < 256; o <<= 1) {
        int t = (tid >= o) ? s[tid - o] : 0;
        __syncthreads();
        s[tid] += t;
        __syncthreads();
    }
    off[tid] = s[tid] - deg[tid];
    cur[tid] = s[tid] - deg[tid];
    __syncthreads();

    int node = b * 256 + tid;
    if (node < N_NODES) {
        rowbeg[node] = base + off[tid];
        rowend[node] = base + off[tid] + deg[tid];
    }

    for (int i = tid; i < cnt; i += 256) {
        u32 rec = binned[base + i];
        int l = (rec >> 16) & 255;
        int p = atomicAdd(&cur[l], 1);
        csr[base + p] = (int)(rec & 0xffffu);
    }
}

// ---------------- MFMA GEMM: x @ W -> hp (bf16) + fused alpha logits ----------
// R10 structure (best measured): W^T staged in LDS once per block.
// 64 rows/block, 4 waves, 8 head-tiles each, K=128 in 4 mfma steps.

template<bool BF16IN>
__launch_bounds__(256)
__global__ void k_gemm(const void* __restrict__ xin, const u16* __restrict__ wt_g,
                       const float* __restrict__ asrc, const float* __restrict__ adst,
                       u16* __restrict__ hp,
                       float* __restrict__ as_, float* __restrict__ ad_){
    __shared__ u16 xs[64 * XSTR];    // 17.0 KB (input tile, then output tile)
    __shared__ u16 wt[128 * XSTR];   // 34.0 KB
    const int tid = threadIdx.x;
    const int r0  = blockIdx.x * 64;

    for (int c = tid; c < 128 * 16; c += 256) {
        int n = c >> 4, ch = c & 15;
        *(uint4*)(wt + n * XSTR + ch * 8) = *(const uint4*)(wt_g + n * 128 + ch * 8);
    }
    if (BF16IN) {
        const u16* x = (const u16*)xin;
        for (int c = tid; c < 64 * 16; c += 256) {
            int row = r0 + (c >> 4);
            uint4 v = make_uint4(0, 0, 0, 0);
            if (row < N_NODES) v = *(const uint4*)(x + (size_t)row * 128 + (c & 15) * 8);
            *(uint4*)(xs + (c >> 4) * XSTR + (c & 15) * 8) = v;
        }
    } else {
        const float* x = (const float*)xin;
        for (int c = tid; c < 64 * 16; c += 256) {
            int row = r0 + (c >> 4);
            u16 t[8] = {0,0,0,0,0,0,0,0};
            if (row < N_NODES) {
                const float* p = x + (size_t)row * 128 + (c & 15) * 8;
                #pragma unroll
                for (int j = 0; j < 8; j++) t[j] = f2b(p[j]);
            }
            *(uint4*)(xs + (c >> 4) * XSTR + (c & 15) * 8) = *(uint4*)t;
        }
    }
    __syncthreads();

    const int lane = tid & 63;
    const int wv   = tid >> 6;
    const int m    = lane & 15;
    const int quad = lane >> 4;

    const u16* arow = xs + (16 * wv + m) * XSTR + quad * 8;
    bf16x8 a0 = *(const bf16x8*)(arow);
    bf16x8 a1 = *(const bf16x8*)(arow + 32);
    bf16x8 a2 = *(const bf16x8*)(arow + 64);
    bf16x8 a3 = *(const bf16x8*)(arow + 96);

    #pragma unroll
    for (int c = 0; c < 8; c++) {
        const u16* brow = wt + (16 * c + m) * XSTR + quad * 8;
        f32x4 acc = {0.f, 0.f, 0.f, 0.f};
        acc = __builtin_amdgcn_mfma_f32_16x16x32_bf16(a0, *(const bf16x8*)(brow),      acc, 0, 0, 0);
        acc = __builtin_amdgcn_mfma_f32_16x16x32_bf16(a1, *(const bf16x8*)(brow + 32), acc, 0, 0, 0);
        acc = __builtin_amdgcn_mfma_f32_16x16x32_bf16(a2, *(const bf16x8*)(brow + 64), acc, 0, 0, 0);
        acc = __builtin_amdgcn_mfma_f32_16x16x32_bf16(a3, *(const bf16x8*)(brow + 96), acc, 0, 0, 0);
        u16* orow = xs + (16 * wv + quad * 4) * XSTR + 16 * c + m;
        orow[0]        = f2b(acc[0]);
        orow[XSTR]     = f2b(acc[1]);
        orow[2 * XSTR] = f2b(acc[2]);
        orow[3 * XSTR] = f2b(acc[3]);
    }
    __syncthreads();

    for (int t = tid; t < 512; t += 256) {
        int row = t >> 3, h = t & 7;
        int gr = r0 + row;
        if (gr >= N_NODES) continue;
        const u16* hr = xs + row * XSTR + h * 16;
        const float* av = asrc + h * 16;
        const float* bv = adst + h * 16;
        float s0 = 0.f, s1 = 0.f;
        #pragma unroll
        for (int j = 0; j < 16; j++) {
            float v = b2f(hr[j]);
            s0 = fmaf(v, av[j], s0);
            s1 = fmaf(v, bv[j], s1);
        }
        as_[(size_t)gr * 8 + h] = s0;
        ad_[(size_t)gr * 8 + h] = s1;
    }

    for (int t = tid; t < 1024; t += 256) {
        int row = t >> 4, ch = t & 15;
        int gr = r0 + row;
        if (gr >= N_NODES) continue;
        *(uint4*)(hp + (size_t)gr * 128 + ch * 8) = *(const uint4*)(xs + row * XSTR + ch * 8);
    }
}

// ---------------- per-layer: single-pass segment softmax + aggregate ----------
// One wave/node; 16 edges in flight per iteration (4 independent gather chains).

__launch_bounds__(256)
__global__ void k_agg(const int* __restrict__ rowbeg, const int* __restrict__ rowend,
                      const int* __restrict__ csr,
                      const float* __restrict__ as_, const float* __restrict__ ad_,
                      const uint4* __restrict__ hp4, const float* __restrict__ bias,
                      u16* __restrict__ xout){
    const int lane = threadIdx.x & 63;
    const int wid  = threadIdx.x >> 6;
    const int n    = blockIdx.x * 4 + wid;
    if (n >= N_NODES) return;
    const int beg = rowbeg[n], end = rowend[n];

    const int q  = lane >> 4;       // edge slot 0..3
    const int li = lane & 15;       // cols 8*li .. 8*li+7
    const int h  = li >> 1;         // head
    const float adn = ad_[(size_t)n * 8 + h];

    float acc[8];
    #pragma unroll
    for (int j = 0; j < 8; j++) acc[j] = 0.f;
    float den = 0.f;

    for (int e0 = beg; e0 < end; e0 += 16) {
        int eA = e0 + q, eB = eA + 4, eC = eA + 8, eD = eA + 12;
        int sA = csr[min(eA, end - 1)];
        int sB = csr[min(eB, end - 1)];
        int sC = csr[min(eC, end - 1)];
        int sD = csr[min(eD, end - 1)];
        float vA = as_[(size_t)sA * 8 + h] + adn;
        float vB = as_[(size_t)sB * 8 + h] + adn;
        float vC = as_[(size_t)sC * 8 + h] + adn;
        float vD = as_[(size_t)sD * 8 + h] + adn;
        uint4 pA = hp4[(size_t)sA * 16 + li];
        uint4 pB = hp4[(size_t)sB * 16 + li];
        uint4 pC = hp4[(size_t)sC * 16 + li];
        uint4 pD = hp4[(size_t)sD * 16 + li];
        vA = vA > 0.f ? vA : NEG_SLOPE * vA;
        vB = vB > 0.f ? vB : NEG_SLOPE * vB;
        vC = vC > 0.f ? vC : NEG_SLOPE * vC;
        vD = vD > 0.f ? vD : NEG_SLOPE * vD;
        float wA = (eA < end) ? __expf(vA) : 0.f;
        float wB = (eB < end) ? __expf(vB) : 0.f;
        float wC = (eC < end) ? __expf(vC) : 0.f;
        float wD = (eD < end) ? __expf(vD) : 0.f;
        den += (wA + wB) + (wC + wD);
        acc[0] = fmaf(wA, b2f((u16)(pA.x & 0xffff)), acc[0]);
        acc[1] = fmaf(wA, b2f((u16)(pA.x >> 16)),    acc[1]);
        acc[2] = fmaf(wA, b2f((u16)(pA.y & 0xffff)), acc[2]);
        acc[3] = fmaf(wA, b2f((u16)(pA.y >> 16)),    acc[3]);
        acc[4] = fmaf(wA, b2f((u16)(pA.z & 0xffff)), acc[4]);
        acc[5] = fmaf(wA, b2f((u16)(pA.z >> 16)),    acc[5]);
        acc[6] = fmaf(wA, b2f((u16)(pA.w & 0xffff)), acc[6]);
        acc[7] = fmaf(wA, b2f((u16)(pA.w >> 16)),    acc[7]);
        acc[0] = fmaf(wB, b2f((u16)(pB.x & 0xffff)), acc[0]);
        acc[1] = fmaf(wB, b2f((u16)(pB.x >> 16)),    acc[1]);
        acc[2] = fmaf(wB, b2f((u16)(pB.y & 0xffff)), acc[2]);
        acc[3] = fmaf(wB, b2f((u16)(pB.y >> 16)),    acc[3]);
        acc[4] = fmaf(wB, b2f((u16)(pB.z & 0xffff)), acc[4]);
        acc[5] = fmaf(wB, b2f((u16)(pB.z >> 16)),    acc[5]);
        acc[6] = fmaf(wB, b2f((u16)(pB.w & 0xffff)), acc[6]);
        acc[7] = fmaf(wB, b2f((u16)(pB.w >> 16)),    acc[7]);
        acc[0] = fmaf(wC, b2f((u16)(pC.x & 0xffff)), acc[0]);
        acc[1] = fmaf(wC, b2f((u16)(pC.x >> 16)),    acc[1]);
        acc[2] = fmaf(wC, b2f((u16)(pC.y & 0xffff)), acc[2]);
        acc[3] = fmaf(wC, b2f((u16)(pC.y >> 16)),    acc[3]);
        acc[4] = fmaf(wC, b2f((u16)(pC.z & 0xffff)), acc[4]);
        acc[5] = fmaf(wC, b2f((u16)(pC.z >> 16)),    acc[5]);
        acc[6] = fmaf(wC, b2f((u16)(pC.w & 0xffff)), acc[6]);
        acc[7] = fmaf(wC, b2f((u16)(pC.w >> 16)),    acc[7]);
        acc[0] = fmaf(wD, b2f((u16)(pD.x & 0xffff)), acc[0]);
        acc[1] = fmaf(wD, b2f((u16)(pD.x >> 16)),    acc[1]);
        acc[2] = fmaf(wD, b2f((u16)(pD.y & 0xffff)), acc[2]);
        acc[3] = fmaf(wD, b2f((u16)(pD.y >> 16)),    acc[3]);
        acc[4] = fmaf(wD, b2f((u16)(pD.z & 0xffff)), acc[4]);
        acc[5] = fmaf(wD, b2f((u16)(pD.z >> 16)),    acc[5]);
        acc[6] = fmaf(wD, b2f((u16)(pD.w & 0xffff)), acc[6]);
        acc[7] = fmaf(wD, b2f((u16)(pD.w >> 16)),    acc[7]);
    }

    #pragma unroll
    for (int j = 0; j < 8; j++) {
        acc[j] += __shfl_xor(acc[j], 16);
        acc[j] += __shfl_xor(acc[j], 32);
    }
    den += __shfl_xor(den, 16);
    den += __shfl_xor(den, 32);

    if (q == 0) {
        const float inv = 1.f / (den + 1e-16f);
        const float4 b0 = *(const float4*)(bias + 8 * li);
        const float4 b1 = *(const float4*)(bias + 8 * li + 4);
        float o[8];
        o[0] = acc[0] * inv + b0.x; o[1] = acc[1] * inv + b0.y;
        o[2] = acc[2] * inv + b0.z; o[3] = acc[3] * inv + b0.w;
        o[4] = acc[4] * inv + b1.x; o[5] = acc[5] * inv + b1.y;
        o[6] = acc[6] * inv + b1.z; o[7] = acc[7] * inv + b1.w;
        #pragma unroll
        for (int j = 0; j < 8; j++)
            o[j] = o[j] > 0.f ? o[j] : (__expf(o[j]) - 1.f);   // ELU
        uint4 p;
        p.x = (u32)f2b(o[0]) | ((u32)f2b(o[1]) << 16);
        p.y = (u32)f2b(o[2]) | ((u32)f2b(o[3]) << 16);
        p.z = (u32)f2b(o[4]) | ((u32)f2b(o[5]) << 16);
        p.w = (u32)f2b(o[6]) | ((u32)f2b(o[7]) << 16);
        *(uint4*)(xout + (size_t)n * 128 + 8 * li) = p;
    }
}

// ---------------- pooling (bf16 input, sorted batch) / fused BN+FC ----------

__global__ void k_pool(const u16* __restrict__ x, const int* __restrict__ batch,
                       float* __restrict__ pooled){
    int tid = threadIdx.x;             // 128 = feature
    int n0 = blockIdx.x * POOL_CHUNK;
    int nend = min(n0 + POOL_CHUNK, N_NODES);
    float acc = 0.f;
    int cur = batch[n0];
    for (int n = n0; n < nend; n++) {
        int g = batch[n];
        if (g != cur) {
            atomicAdd(&pooled[cur * 128 + tid], acc);
            acc = 0.f; cur = g;
        }
        acc += b2f(x[(size_t)n * 128 + tid]);
    }
    atomicAdd(&pooled[cur * 128 + tid], acc);
}

// one block per graph; per-block redundant BN stats (pooled is 51KB, L2-hot)
__launch_bounds__(128)
__global__ void k_bnfc(const float* __restrict__ pooled, const float* __restrict__ gamma,
                       const float* __restrict__ beta, const float* __restrict__ fw,
                       const float* __restrict__ fb, float* __restrict__ out){
    __shared__ float sn[128];
    const int g = blockIdx.x, f = threadIdx.x;
    float mu = 0.f;
    for (int i = 0; i < NGRAPH; i++) mu += pooled[i * 128 + f];
    mu *= (1.f / NGRAPH);
    float var = 0.f;
    for (int i = 0; i < NGRAPH; i++) { float d = pooled[i * 128 + f] - mu; var += d * d; }
    var *= (1.f / NGRAPH);
    const float rs = rsqrtf(var + BN_EPS);
    sn[f] = (pooled[g * 128 + f] - mu) * rs * gamma[f] + beta[f];
    __syncthreads();
    if (f < NLAT) {
        float acc = fb[f];
        const float4* wr = (const float4*)(fw + f * 128);
        #pragma unroll
        for (int k = 0; k < 32; k++) {
            float4 w = wr[k];
            const float* nv = sn + 4 * k;
            acc = fmaf(nv[0], w.x, acc);
            acc = fmaf(nv[1], w.y, acc);
            acc = fmaf(nv[2], w.z, acc);
            acc = fmaf(nv[3], w.w, acc);
        }
        out[g * 64 + f] = acc;
    }
}

// ---------------- launch ----------------

extern "C" void kernel_launch(void* const* d_in, const int* in_sizes, int n_in,
                              void* d_out, int out_size, void* d_ws, size_t ws_size,
                              hipStream_t stream) {
    const float* x0    = (const float*)d_in[0];
    const int*   ei    = (const int*)d_in[1];
    const int*   batch = (const int*)d_in[2];
    const float* Wp    = (const float*)d_in[3];
    const float* asrc  = (const float*)d_in[4];
    const float* adst  = (const float*)d_in[5];
    const float* bias  = (const float*)d_in[6];
    const float* gamma = (const float*)d_in[7];
    const float* beta  = (const float*)d_in[8];
    const float* fw    = (const float*)d_in[9];
    const float* fb    = (const float*)d_in[10];
    float* out = (float*)d_out;

    char* w = (char*)d_ws;
    size_t off = 0;
    auto take = [&](size_t bytes) -> char* {
        char* p = w + off;
        off += (bytes + 255) & ~(size_t)255;
        return p;
    };
    int*   rowbeg  = (int*)take((size_t)N_NODES * 4);
    int*   rowend  = (int*)take((size_t)N_NODES * 4);
    int*   bucket_cur = (int*)take(NBUCKET * 4);
    u32*   binned  = (u32*)take((size_t)NBUCKET * CAP * 4);
    int*   csr     = (int*)take((size_t)NBUCKET * CAP * 4);
    u16*   wt_g    = (u16*)take((size_t)3 * 128 * 128 * 2);
    u16*   hp      = (u16*)take((size_t)N_NODES * 128 * 2);
    float* as_     = (float*)take((size_t)N_NODES * 8 * 4);
    float* ad_     = (float*)take((size_t)N_NODES * 8 * 4);
    u16*   xb1     = (u16*)take((size_t)N_NODES * 128 * 2);
    u16*   xb2     = (u16*)take((size_t)N_NODES * 128 * 2);
    float* pooled  = (float*)take((size_t)NGRAPH * 128 * 4);

    // prelude (W transpose + zero bucket_cur/pooled), then binned CSR build
    k_pre   <<<24, 256, 0, stream>>>(Wp, wt_g, bucket_cur, pooled);
    k_bin   <<<(N_ETOT + EPB - 1) / EPB, 256, 0, stream>>>(ei, bucket_cur, binned);
    k_bucket<<<NBUCKET, 256, 0, stream>>>(bucket_cur, binned, rowbeg, rowend, csr);

    const int gblk = (N_NODES + 63) / 64;
    const int ablk = (N_NODES + 3) / 4;

    // layer 0 (fp32 input)
    k_gemm<false><<<gblk, 256, 0, stream>>>(x0, wt_g, asrc, adst, hp, as_, ad_);
    k_agg<<<ablk, 256, 0, stream>>>(rowbeg, rowend, csr, as_, ad_,
                                    (const uint4*)hp, bias, xb1);
    // layer 1 (bf16 input)
    k_gemm<true><<<gblk, 256, 0, stream>>>(xb1, wt_g + 16384, asrc + 128, adst + 128,
                                           hp, as_, ad_);
    k_agg<<<ablk, 256, 0, stream>>>(rowbeg, rowend, csr, as_, ad_,
                                    (const uint4*)hp, bias + 128, xb2);
    // layer 2 (bf16 input)
    k_gemm<true><<<gblk, 256, 0, stream>>>(xb2, wt_g + 32768, asrc + 256, adst + 256,
                                           hp, as_, ad_);
    k_agg<<<ablk, 256, 0, stream>>>(rowbeg, rowend, csr, as_, ad_,
                                    (const uint4*)hp, bias + 256, xb1);

    // pool -> fused BN+FC
    k_pool<<<(N_NODES + POOL_CHUNK - 1) / POOL_CHUNK, 128, 0, stream>>>(xb1, batch, pooled);
    k_bnfc<<<NGRAPH, 128, 0, stream>>>(pooled, gamma, beta, fw, fb, out);
}